// Round 3
// baseline (9494.053 us; speedup 1.0000x reference)
//
#include <hip/hip_runtime.h>
#include <math.h>

// Problem dims (fixed)
#define B_ 64
#define F_ 256
#define T_ 1024
#define H_ 1024
#define O_ 512
#define NWG 64   // persistent-grid workgroups (== wavefront size; 64 blocks << 256 CUs)

typedef short short8 __attribute__((ext_vector_type(8)));   // 8 x bf16 (4 VGPRs)
typedef float f32x4 __attribute__((ext_vector_type(4)));    // MFMA accumulator

__device__ inline float bf2f(unsigned short u) {
    union { unsigned int i; float f; } v; v.i = ((unsigned int)u) << 16; return v.f;
}
__device__ inline unsigned short f2bf(float f) {
    union { float f; unsigned int i; } v; v.f = f;
    unsigned int i = v.i;
    unsigned int r = (i + 0x7fffu + ((i >> 16) & 1u)) >> 16;  // RNE
    return (unsigned short)r;
}

// ---------------------------------------------------------------------------
// Generic fp32 (K x N) -> bf16 (N x K) tile transpose.  src[k][n] -> dst[n][k]
// grid: (N/32, K/32), block: (32, 8)
// ---------------------------------------------------------------------------
__global__ void wt_transpose(const float* __restrict__ src,
                             unsigned short* __restrict__ dst, int K, int N) {
    __shared__ float tile[32][33];
    int n0 = blockIdx.x * 32, k0 = blockIdx.y * 32;
    int tx = threadIdx.x, ty = threadIdx.y;
    for (int i = ty; i < 32; i += 8)
        tile[i][tx] = src[(size_t)(k0 + i) * N + n0 + tx];
    __syncthreads();
    for (int i = ty; i < 32; i += 8)
        dst[(size_t)(n0 + i) * K + k0 + tx] = f2bf(tile[tx][i]);
}

// ---------------------------------------------------------------------------
// x (B,F,T) fp32 -> xT (T,B,F) bf16.  grid: 64*4*16 = 4096 blocks, 256 thr
// ---------------------------------------------------------------------------
__global__ void xpose_x(const float* __restrict__ x, unsigned short* __restrict__ xT) {
    __shared__ float tile[64][65];
    int id = blockIdx.x;
    int b = id >> 6;            // 0..63
    int ft = (id >> 4) & 3;     // 0..3   (F/64)
    int tt = id & 15;           // 0..15  (T/64)
    int f0 = ft * 64, t0 = tt * 64;
    for (int i = threadIdx.x; i < 64 * 64; i += 256) {
        int fl = i >> 6, tl = i & 63;
        tile[fl][tl] = x[((size_t)(b * F_ + f0 + fl)) * T_ + t0 + tl];
    }
    __syncthreads();
    for (int i = threadIdx.x; i < 64 * 64; i += 256) {
        int tl = i >> 6, fl = i & 63;
        xT[((size_t)(t0 + tl) * B_ + b) * F_ + f0 + fl] = f2bf(tile[fl][tl]);
    }
}

// ---------------------------------------------------------------------------
// Input projection: S[r][h] = bf16( xT[r][:] @ Wx[:,h] + b[h] ),  r = t*64+b
// grid: (16, 1024)  block: 256 (4 waves); block tile 64 rows x 64 cols
// MFMA 16x16x32 layouts (HW-verified):
//   A frag: m = lane&15, k = (lane>>4)*8 + j
//   B frag: n = lane&15, k = (lane>>4)*8 + j
//   C/D   : col = lane&15, row = (lane>>4)*4 + r
// ---------------------------------------------------------------------------
__global__ __launch_bounds__(256) void proj_kernel(
    const unsigned short* __restrict__ xT, const unsigned short* __restrict__ WxT,
    const float* __restrict__ bias, unsigned short* __restrict__ S) {
    int nb = blockIdx.x;   // 0..15
    int mb = blockIdx.y;   // 0..1023
    int wave = threadIdx.x >> 6, lane = threadIdx.x & 63;
    int col16 = lane & 15, quad = lane >> 4;
    int m0 = mb * 64 + wave * 16;
    int n0 = nb * 64;

    f32x4 acc[4];
    for (int s = 0; s < 4; ++s)
        for (int r = 0; r < 4; ++r) acc[s][r] = 0.0f;

    #pragma unroll
    for (int kc = 0; kc < F_ / 32; ++kc) {
        int k0 = kc * 32 + quad * 8;
        short8 a = *reinterpret_cast<const short8*>(xT + (size_t)(m0 + col16) * F_ + k0);
        #pragma unroll
        for (int s = 0; s < 4; ++s) {
            short8 bfr = *reinterpret_cast<const short8*>(
                WxT + (size_t)(n0 + s * 16 + col16) * F_ + k0);
            acc[s] = __builtin_amdgcn_mfma_f32_16x16x32_bf16(a, bfr, acc[s], 0, 0, 0);
        }
    }
    #pragma unroll
    for (int s = 0; s < 4; ++s) {
        int col = n0 + s * 16 + col16;
        float bb = bias[col];
        #pragma unroll
        for (int r = 0; r < 4; ++r) {
            int row = m0 + quad * 4 + r;
            S[(size_t)row * H_ + col] = f2bf(acc[s][r] + bb);
        }
    }
}

// ---------------------------------------------------------------------------
// Zero the barrier flags (64 flags, 64B stride). Runs each launch (re-poison safe).
// ---------------------------------------------------------------------------
__global__ void init_flags(unsigned int* flags) {
    if (threadIdx.x < NWG) flags[threadIdx.x * 16] = 0;
}

// ---------------------------------------------------------------------------
// Persistent recurrence kernel: all T steps in ONE dispatch (plain launch —
// 64 blocks @ 1 block/CU on 256 CUs are trivially co-resident; bounded-spin
// guard converts any pathological non-residency into fast wrong-answer, not hang).
//   St[b][n] = bf16( tanh( xp_t[b][n] + h_{t-1}[b][:] @ Wh[:,n] ) )
// Partitioning: 64 WGs x 16 columns each; 4 waves x 16 rows each (B=64 rows).
// Wh column slice register-resident: 32 x short8 B-fragments = 128 VGPRs/lane.
// Grid barrier: flags[wg] = completed-step count (monotone). One agent-scope
// release store per WG; wave 0 polls all 64 flags (one lane each, acquire).
// ---------------------------------------------------------------------------
__global__ __launch_bounds__(256, 1) void rnn_persistent(
    unsigned short* __restrict__ S, const unsigned short* __restrict__ WhT,
    unsigned int* flags) {
    const int wg = blockIdx.x;                 // 0..63
    const int wave = threadIdx.x >> 6;         // 0..3
    const int lane = threadIdx.x & 63;
    const int col16 = lane & 15, quad = lane >> 4;
    const int n0 = wg * (H_ / NWG);            // 16 columns per WG
    const int m0 = wave * 16;                  // 16 rows per wave

    // Load this WG's Wh column slice into registers: 32 B-fragments (128 VGPRs)
    short8 bw[32];
    #pragma unroll
    for (int kc = 0; kc < 32; ++kc)
        bw[kc] = *reinterpret_cast<const short8*>(
            WhT + (size_t)(n0 + col16) * H_ + kc * 32 + quad * 8);

    // ---- t = 0: h0 = tanh(xp0)  (s0 = 0, no matmul) ----
    #pragma unroll
    for (int r = 0; r < 4; ++r) {
        size_t idx = (size_t)(m0 + quad * 4 + r) * H_ + n0 + col16;
        S[idx] = f2bf(tanhf(bf2f(S[idx])));
    }
    __syncthreads();
    if (threadIdx.x == 0)
        __hip_atomic_store(&flags[wg * 16], 1u, __ATOMIC_RELEASE,
                           __HIP_MEMORY_SCOPE_AGENT);

    int dead = 0;   // barrier safety-net state (wave 0, lane-uniform)

    for (int t = 1; t < T_; ++t) {
        const unsigned short* __restrict__ Sp = S + (size_t)(t - 1) * (B_ * H_);
        unsigned short* __restrict__ St = S + (size_t)t * (B_ * H_);

        // Prefetch xp tile (this WG's own columns of S[t] — written only by
        // proj_kernel and later by THIS WG; no race): overlaps the barrier wait.
        float xp[4];
        #pragma unroll
        for (int r = 0; r < 4; ++r)
            xp[r] = bf2f(St[(size_t)(m0 + quad * 4 + r) * H_ + n0 + col16]);

        // ---- grid barrier: wait until every WG finished step t-1 ----
        if (wave == 0 && !dead) {
            const unsigned tgt = (unsigned)t;
            int guard = 0;
            while (true) {
                unsigned v = __hip_atomic_load(&flags[lane * 16], __ATOMIC_ACQUIRE,
                                               __HIP_MEMORY_SCOPE_AGENT);
                if (__ballot(v >= tgt) == ~0ull) break;
                __builtin_amdgcn_s_sleep(1);
                if (++guard > (1 << 18)) { dead = 1; break; }  // fail fast, never hang
            }
        }
        __syncthreads();

        // ---- 64x16 tile: xp + h_{t-1} @ Wh[:, n0:n0+16] ----
        f32x4 acc0 = {0.f, 0.f, 0.f, 0.f};
        f32x4 acc1 = {0.f, 0.f, 0.f, 0.f};
        const unsigned short* __restrict__ arow =
            Sp + (size_t)(m0 + col16) * H_ + quad * 8;
        #pragma unroll
        for (int kc = 0; kc < 32; kc += 2) {
            short8 a0 = *reinterpret_cast<const short8*>(arow + kc * 32);
            short8 a1 = *reinterpret_cast<const short8*>(arow + (kc + 1) * 32);
            acc0 = __builtin_amdgcn_mfma_f32_16x16x32_bf16(a0, bw[kc], acc0, 0, 0, 0);
            acc1 = __builtin_amdgcn_mfma_f32_16x16x32_bf16(a1, bw[kc + 1], acc1, 0, 0, 0);
        }
        #pragma unroll
        for (int r = 0; r < 4; ++r) {
            float h = tanhf(xp[r] + acc0[r] + acc1[r]);
            St[(size_t)(m0 + quad * 4 + r) * H_ + n0 + col16] = f2bf(h);
        }
        __syncthreads();
        if (threadIdx.x == 0)
            __hip_atomic_store(&flags[wg * 16], (unsigned)(t + 1), __ATOMIC_RELEASE,
                               __HIP_MEMORY_SCOPE_AGENT);
    }
}

// ---------------------------------------------------------------------------
// Output projection: out[b][t][o] = S[t*64+b][:] @ Wout[:,o] + bout[o]
// grid: (8, 1024); block 256 (4 waves); block tile = one t (64 b-rows) x 64 cols
// ---------------------------------------------------------------------------
__global__ __launch_bounds__(256) void out_kernel(
    const unsigned short* __restrict__ S, const unsigned short* __restrict__ WoutT,
    const float* __restrict__ bout, float* __restrict__ out) {
    int nb = blockIdx.x;   // 0..7
    int tt = blockIdx.y;   // 0..1023 (= t)
    int wave = threadIdx.x >> 6, lane = threadIdx.x & 63;
    int col16 = lane & 15, quad = lane >> 4;
    int m0 = tt * 64 + wave * 16;
    int n0 = nb * 64;

    f32x4 acc[4];
    for (int s = 0; s < 4; ++s)
        for (int r = 0; r < 4; ++r) acc[s][r] = 0.0f;

    #pragma unroll 4
    for (int kc = 0; kc < H_ / 32; ++kc) {
        int k0 = kc * 32 + quad * 8;
        short8 a = *reinterpret_cast<const short8*>(S + (size_t)(m0 + col16) * H_ + k0);
        #pragma unroll
        for (int s = 0; s < 4; ++s) {
            short8 bfr = *reinterpret_cast<const short8*>(
                WoutT + (size_t)(n0 + s * 16 + col16) * H_ + k0);
            acc[s] = __builtin_amdgcn_mfma_f32_16x16x32_bf16(a, bfr, acc[s], 0, 0, 0);
        }
    }
    #pragma unroll
    for (int s = 0; s < 4; ++s) {
        int col = n0 + s * 16 + col16;
        float bo = bout[col];
        #pragma unroll
        for (int r = 0; r < 4; ++r) {
            int bidx = wave * 16 + quad * 4 + r;   // batch index within this t
            out[((size_t)bidx * T_ + tt) * O_ + col] = acc[s][r] + bo;
        }
    }
}

// ---------------------------------------------------------------------------
extern "C" void kernel_launch(void* const* d_in, const int* in_sizes, int n_in,
                              void* d_out, int out_size, void* d_ws, size_t ws_size,
                              hipStream_t stream) {
    const float* x    = (const float*)d_in[0];   // (B,F,T)
    const float* Wx   = (const float*)d_in[1];   // (F,H)
    const float* Wh   = (const float*)d_in[2];   // (H,H)
    const float* bias = (const float*)d_in[3];   // (H)
    const float* Wout = (const float*)d_in[4];   // (H,O)
    const float* bout = (const float*)d_in[5];   // (O)
    float* out = (float*)d_out;

    // workspace layout (bf16 = ushort), total ~131.5 MB
    unsigned short* WhT   = (unsigned short*)d_ws;             // H x H   [n][k]
    unsigned short* WxT   = WhT + (size_t)H_ * H_;             // H x F   [n][k]
    unsigned short* WoutT = WxT + (size_t)H_ * F_;             // O x H   [n][k]
    unsigned short* S     = WoutT + (size_t)O_ * H_;           // T x B x H (xp -> states, in place)
    unsigned short* xT    = (unsigned short*)d_out;            // T x B x F scratch (32MB, consumed by proj)
    // barrier flags: in d_out past xT scratch (out_kernel overwrites later — safe)
    unsigned int* flags   = (unsigned int*)((char*)d_out + (32u << 20));

    wt_transpose<<<dim3(H_ / 32, H_ / 32), dim3(32, 8), 0, stream>>>(Wh, WhT, H_, H_);
    wt_transpose<<<dim3(H_ / 32, F_ / 32), dim3(32, 8), 0, stream>>>(Wx, WxT, F_, H_);
    wt_transpose<<<dim3(O_ / 32, H_ / 32), dim3(32, 8), 0, stream>>>(Wout, WoutT, H_, O_);
    xpose_x<<<dim3(4096), dim3(256), 0, stream>>>(x, xT);
    init_flags<<<1, 64, 0, stream>>>(flags);

    proj_kernel<<<dim3(16, 1024), dim3(256), 0, stream>>>(xT, WxT, bias, S);

    // all T recurrence steps in one persistent-grid dispatch (plain launch:
    // no cooperative-launch graph-capture hazard; 64 blocks are co-resident)
    rnn_persistent<<<dim3(NWG), dim3(256), 0, stream>>>(S, WhT, flags);

    out_kernel<<<dim3(8, 1024), dim3(256), 0, stream>>>(S, WoutT, bout, out);
}

// Round 4
// 7659.721 us; speedup vs baseline: 1.2395x; 1.2395x over previous
//
#include <hip/hip_runtime.h>
#include <math.h>

// Problem dims (fixed)
#define B_ 64
#define F_ 256
#define T_ 1024
#define H_ 1024
#define O_ 512
#define NWG 64   // persistent-grid workgroups (== wavefront size; 64 blocks << 256 CUs)

// Blocked state layout: S2[t][nblk][b][c], nblk = col/16 (64 blocks), c = col%16.
// Each RNN workgroup owns exactly one 2KB [b][c] block per timestep -> no
// cross-XCD false sharing, contiguous writeback, contiguous A-load segments.
#define S2_TSTRIDE (64 * 64 * 16)   // = B_*H_ elems per timestep

typedef short short8 __attribute__((ext_vector_type(8)));   // 8 x bf16 (4 VGPRs)
typedef float f32x4 __attribute__((ext_vector_type(4)));    // MFMA accumulator

__device__ inline float bf2f(unsigned short u) {
    union { unsigned int i; float f; } v; v.i = ((unsigned int)u) << 16; return v.f;
}
__device__ inline unsigned short f2bf(float f) {
    union { float f; unsigned int i; } v; v.f = f;
    unsigned int i = v.i;
    unsigned int r = (i + 0x7fffu + ((i >> 16) & 1u)) >> 16;  // RNE
    return (unsigned short)r;
}

// ---------------------------------------------------------------------------
// Generic fp32 (K x N) -> bf16 (N x K) tile transpose.  src[k][n] -> dst[n][k]
// grid: (N/32, K/32), block: (32, 8)
// ---------------------------------------------------------------------------
__global__ void wt_transpose(const float* __restrict__ src,
                             unsigned short* __restrict__ dst, int K, int N) {
    __shared__ float tile[32][33];
    int n0 = blockIdx.x * 32, k0 = blockIdx.y * 32;
    int tx = threadIdx.x, ty = threadIdx.y;
    for (int i = ty; i < 32; i += 8)
        tile[i][tx] = src[(size_t)(k0 + i) * N + n0 + tx];
    __syncthreads();
    for (int i = ty; i < 32; i += 8)
        dst[(size_t)(n0 + i) * K + k0 + tx] = f2bf(tile[tx][i]);
}

// ---------------------------------------------------------------------------
// x (B,F,T) fp32 -> xT (T,B,F) bf16.  grid: 64*4*16 = 4096 blocks, 256 thr
// ---------------------------------------------------------------------------
__global__ void xpose_x(const float* __restrict__ x, unsigned short* __restrict__ xT) {
    __shared__ float tile[64][65];
    int id = blockIdx.x;
    int b = id >> 6;            // 0..63
    int ft = (id >> 4) & 3;     // 0..3   (F/64)
    int tt = id & 15;           // 0..15  (T/64)
    int f0 = ft * 64, t0 = tt * 64;
    for (int i = threadIdx.x; i < 64 * 64; i += 256) {
        int fl = i >> 6, tl = i & 63;
        tile[fl][tl] = x[((size_t)(b * F_ + f0 + fl)) * T_ + t0 + tl];
    }
    __syncthreads();
    for (int i = threadIdx.x; i < 64 * 64; i += 256) {
        int tl = i >> 6, fl = i & 63;
        xT[((size_t)(t0 + tl) * B_ + b) * F_ + f0 + fl] = f2bf(tile[fl][tl]);
    }
}

// ---------------------------------------------------------------------------
// Input projection into blocked layout:
//   S2[t][nblk][b][c] = bf16( xT[t*64+b][:] @ Wx[:, nblk*16+c] + bias )
// grid: (16, 1024)  block: 256 (4 waves); block tile 64 rows x 64 cols
// MFMA 16x16x32 layouts (HW-verified):
//   A frag: m = lane&15, k = (lane>>4)*8 + j
//   B frag: n = lane&15, k = (lane>>4)*8 + j
//   C/D   : col = lane&15, row = (lane>>4)*4 + r
// ---------------------------------------------------------------------------
__global__ __launch_bounds__(256) void proj_kernel(
    const unsigned short* __restrict__ xT, const unsigned short* __restrict__ WxT,
    const float* __restrict__ bias, unsigned short* __restrict__ S) {
    int nb = blockIdx.x;   // 0..15
    int mb = blockIdx.y;   // 0..1023 (= t)
    int wave = threadIdx.x >> 6, lane = threadIdx.x & 63;
    int col16 = lane & 15, quad = lane >> 4;
    int m0 = mb * 64 + wave * 16;
    int n0 = nb * 64;

    f32x4 acc[4];
    for (int s = 0; s < 4; ++s)
        for (int r = 0; r < 4; ++r) acc[s][r] = 0.0f;

    #pragma unroll
    for (int kc = 0; kc < F_ / 32; ++kc) {
        int k0 = kc * 32 + quad * 8;
        short8 a = *reinterpret_cast<const short8*>(xT + (size_t)(m0 + col16) * F_ + k0);
        #pragma unroll
        for (int s = 0; s < 4; ++s) {
            short8 bfr = *reinterpret_cast<const short8*>(
                WxT + (size_t)(n0 + s * 16 + col16) * F_ + k0);
            acc[s] = __builtin_amdgcn_mfma_f32_16x16x32_bf16(a, bfr, acc[s], 0, 0, 0);
        }
    }
    #pragma unroll
    for (int s = 0; s < 4; ++s) {
        int col = n0 + s * 16 + col16;
        float bb = bias[col];
        int nblk = (n0 >> 4) + s;
        #pragma unroll
        for (int r = 0; r < 4; ++r) {
            int brow = wave * 16 + quad * 4 + r;   // batch row within this t
            S[((size_t)mb * 64 + nblk) * 1024 + (size_t)brow * 16 + col16] =
                f2bf(acc[s][r] + bb);
        }
    }
}

// ---------------------------------------------------------------------------
// Zero the barrier flags (64 flags, 64B stride). Runs each launch (re-poison safe).
// ---------------------------------------------------------------------------
__global__ void init_flags(unsigned int* flags) {
    if (threadIdx.x < NWG) flags[threadIdx.x * 16] = 0;
}

// ---------------------------------------------------------------------------
// Persistent recurrence kernel: all T steps in ONE dispatch.
//   h_t[b][n] = tanh( xp_t[b][n] + h_{t-1}[b][:] @ Wh[:,n] ),  stored blocked.
// 64 WGs x 16 columns (one S2 block) each; 4 waves x 16 rows each.
// Wh slice PINNED in VGPRs via empty asm (compiler cannot rematerialize).
// Barrier: RELAXED agent-scope flag polls (sc1 LLC reads, NO per-poll cache
// invalidate) + ONE acquire fence per step after success. Release store per
// WG per step (single wbL2). Bounded spin -> fast wrong-answer, never hang.
// ---------------------------------------------------------------------------
__global__ __launch_bounds__(256, 1) void rnn_persistent(
    unsigned short* __restrict__ S, const unsigned short* __restrict__ WhT,
    unsigned int* flags) {
    const int wg = blockIdx.x;                 // 0..63  (owns S2 block nblk = wg)
    const int wave = threadIdx.x >> 6;         // 0..3
    const int lane = threadIdx.x & 63;
    const int col16 = lane & 15, quad = lane >> 4;
    const int n0 = wg * 16;                    // 16 columns per WG
    const int m0 = wave * 16;                  // 16 rows per wave

    // Load this WG's Wh column slice into registers: 32 B-fragments (128 VGPRs)
    short8 bw[32];
    #pragma unroll
    for (int kc = 0; kc < 32; ++kc)
        bw[kc] = *reinterpret_cast<const short8*>(
            WhT + (size_t)(n0 + col16) * H_ + kc * 32 + quad * 8);
    // Pin: values become asm-defined -> compiler must keep them live in VGPRs,
    // cannot sink the loads into the t-loop (round-3 counters: VGPR=88 proved
    // it was re-loading Wh every step through invalidated caches).
    #pragma unroll
    for (int kc = 0; kc < 32; ++kc)
        asm volatile("" : "+v"(bw[kc]));

    // ---- t = 0: h0 = tanh(xp0)  (s0 = 0, no matmul) ----
    {
        unsigned short* St0 = S + (size_t)wg * 1024;
        #pragma unroll
        for (int r = 0; r < 4; ++r) {
            size_t idx = (size_t)(m0 + quad * 4 + r) * 16 + col16;
            St0[idx] = f2bf(tanhf(bf2f(St0[idx])));
        }
    }
    __syncthreads();
    if (threadIdx.x == 0)
        __hip_atomic_store(&flags[wg * 16], 1u, __ATOMIC_RELEASE,
                           __HIP_MEMORY_SCOPE_AGENT);

    int dead = 0;   // barrier safety-net state (wave 0, lane-uniform)

    for (int t = 1; t < T_; ++t) {
        const unsigned short* __restrict__ Sp = S + (size_t)(t - 1) * S2_TSTRIDE;
        unsigned short* __restrict__ St = S + (size_t)t * S2_TSTRIDE;

        // Prefetch xp tile (this WG's own block of S2[t] — written only by
        // proj_kernel and later by THIS WG; no race): overlaps the barrier wait.
        unsigned short* Stb = St + (size_t)wg * 1024;
        float xp[4];
        #pragma unroll
        for (int r = 0; r < 4; ++r)
            xp[r] = bf2f(Stb[(size_t)(m0 + quad * 4 + r) * 16 + col16]);

        // ---- grid barrier: wait until every WG finished step t-1 ----
        if (wave == 0 && !dead) {
            const unsigned tgt = (unsigned)t;
            int guard = 0;
            while (true) {
                // RELAXED agent load: sc1 read from LLC, no cache invalidate
                unsigned v = __hip_atomic_load(&flags[lane * 16], __ATOMIC_RELAXED,
                                               __HIP_MEMORY_SCOPE_AGENT);
                if (__ballot(v >= tgt) == ~0ull) break;
                __builtin_amdgcn_s_sleep(1);
                if (++guard > (1 << 18)) { dead = 1; break; }  // fail fast, never hang
            }
            // ONE invalidate per step (was: one per poll iteration)
            __builtin_amdgcn_fence(__ATOMIC_ACQUIRE, "agent");
        }
        __syncthreads();

        // ---- 64x16 tile: xp + h_{t-1} @ Wh[:, n0:n0+16] ----
        // A-load from blocked layout: k0 = kc*32 + quad*8 ->
        //   elem off = kc*2048 + (quad>>1)*1024 + (m0+col16)*16 + (quad&1)*8
        f32x4 acc0 = {0.f, 0.f, 0.f, 0.f};
        f32x4 acc1 = {0.f, 0.f, 0.f, 0.f};
        const unsigned short* __restrict__ arow =
            Sp + (size_t)(quad >> 1) * 1024 + (size_t)(m0 + col16) * 16 + (quad & 1) * 8;
        #pragma unroll
        for (int kc = 0; kc < 32; kc += 2) {
            short8 a0 = *reinterpret_cast<const short8*>(arow + (size_t)kc * 2048);
            short8 a1 = *reinterpret_cast<const short8*>(arow + (size_t)(kc + 1) * 2048);
            acc0 = __builtin_amdgcn_mfma_f32_16x16x32_bf16(a0, bw[kc], acc0, 0, 0, 0);
            acc1 = __builtin_amdgcn_mfma_f32_16x16x32_bf16(a1, bw[kc + 1], acc1, 0, 0, 0);
        }
        #pragma unroll
        for (int r = 0; r < 4; ++r) {
            float h = tanhf(xp[r] + acc0[r] + acc1[r]);
            Stb[(size_t)(m0 + quad * 4 + r) * 16 + col16] = f2bf(h);
        }
        __syncthreads();
        if (threadIdx.x == 0)
            __hip_atomic_store(&flags[wg * 16], (unsigned)(t + 1), __ATOMIC_RELEASE,
                               __HIP_MEMORY_SCOPE_AGENT);
    }
}

// ---------------------------------------------------------------------------
// Output projection: out[b][t][o] = S2row[t][b][:] @ Wout[:,o] + bout[o]
// A read from blocked S2 layout. grid: (8, 1024); block 256 (4 waves).
// ---------------------------------------------------------------------------
__global__ __launch_bounds__(256) void out_kernel(
    const unsigned short* __restrict__ S, const unsigned short* __restrict__ WoutT,
    const float* __restrict__ bout, float* __restrict__ out) {
    int nb = blockIdx.x;   // 0..7
    int tt = blockIdx.y;   // 0..1023 (= t)
    int wave = threadIdx.x >> 6, lane = threadIdx.x & 63;
    int col16 = lane & 15, quad = lane >> 4;
    int n0 = nb * 64;

    f32x4 acc[4];
    for (int s = 0; s < 4; ++s)
        for (int r = 0; r < 4; ++r) acc[s][r] = 0.0f;

    // A row = batch row (wave*16 + col16) of timestep tt, blocked layout
    const unsigned short* __restrict__ arow =
        S + (size_t)tt * S2_TSTRIDE + (size_t)(quad >> 1) * 1024 +
        (size_t)(wave * 16 + col16) * 16 + (quad & 1) * 8;

    #pragma unroll 4
    for (int kc = 0; kc < H_ / 32; ++kc) {
        int k0 = kc * 32 + quad * 8;
        short8 a = *reinterpret_cast<const short8*>(arow + (size_t)kc * 2048);
        #pragma unroll
        for (int s = 0; s < 4; ++s) {
            short8 bfr = *reinterpret_cast<const short8*>(
                WoutT + (size_t)(n0 + s * 16 + col16) * H_ + k0);
            acc[s] = __builtin_amdgcn_mfma_f32_16x16x32_bf16(a, bfr, acc[s], 0, 0, 0);
        }
    }
    #pragma unroll
    for (int s = 0; s < 4; ++s) {
        int col = n0 + s * 16 + col16;
        float bo = bout[col];
        #pragma unroll
        for (int r = 0; r < 4; ++r) {
            int bidx = wave * 16 + quad * 4 + r;   // batch index within this t
            out[((size_t)bidx * T_ + tt) * O_ + col] = acc[s][r] + bo;
        }
    }
}

// ---------------------------------------------------------------------------
extern "C" void kernel_launch(void* const* d_in, const int* in_sizes, int n_in,
                              void* d_out, int out_size, void* d_ws, size_t ws_size,
                              hipStream_t stream) {
    const float* x    = (const float*)d_in[0];   // (B,F,T)
    const float* Wx   = (const float*)d_in[1];   // (F,H)
    const float* Wh   = (const float*)d_in[2];   // (H,H)
    const float* bias = (const float*)d_in[3];   // (H)
    const float* Wout = (const float*)d_in[4];   // (H,O)
    const float* bout = (const float*)d_in[5];   // (O)
    float* out = (float*)d_out;

    // workspace layout (bf16 = ushort), total ~131.5 MB
    unsigned short* WhT   = (unsigned short*)d_ws;             // H x H   [n][k]
    unsigned short* WxT   = WhT + (size_t)H_ * H_;             // H x F   [n][k]
    unsigned short* WoutT = WxT + (size_t)H_ * F_;             // O x H   [n][k]
    unsigned short* S     = WoutT + (size_t)O_ * H_;           // blocked S2: T x 64 x 64 x 16
    unsigned short* xT    = (unsigned short*)d_out;            // T x B x F scratch (32MB, consumed by proj)
    // barrier flags: in d_out past xT scratch (out_kernel overwrites later — safe)
    unsigned int* flags   = (unsigned int*)((char*)d_out + (32u << 20));

    wt_transpose<<<dim3(H_ / 32, H_ / 32), dim3(32, 8), 0, stream>>>(Wh, WhT, H_, H_);
    wt_transpose<<<dim3(H_ / 32, F_ / 32), dim3(32, 8), 0, stream>>>(Wx, WxT, F_, H_);
    wt_transpose<<<dim3(O_ / 32, H_ / 32), dim3(32, 8), 0, stream>>>(Wout, WoutT, H_, O_);
    xpose_x<<<dim3(4096), dim3(256), 0, stream>>>(x, xT);
    init_flags<<<1, 64, 0, stream>>>(flags);

    proj_kernel<<<dim3(16, 1024), dim3(256), 0, stream>>>(xT, WxT, bias, S);

    // all T recurrence steps in one persistent-grid dispatch
    rnn_persistent<<<dim3(NWG), dim3(256), 0, stream>>>(S, WhT, flags);

    out_kernel<<<dim3(8, 1024), dim3(256), 0, stream>>>(S, WoutT, bout, out);
}

// Round 5
// 7522.428 us; speedup vs baseline: 1.2621x; 1.0183x over previous
//
#include <hip/hip_runtime.h>
#include <math.h>

// Problem dims (fixed)
#define B_ 64
#define F_ 256
#define T_ 1024
#define H_ 1024
#define O_ 512

// RNN grid: 4 row-groups (16 batch rows each) x 16 col-groups (64 cols each)
#define RG_ 4
#define CG_ 16
#define NWG (RG_ * CG_)

// Blocked state layout S3[t][rg][cg][mr=16][c=64] (elems):
//   elem(t,b,n) = t*65536 + (b>>4)*16384 + (n>>6)*1024 + (b&15)*64 + (n&63)
// Each RNN WG owns one contiguous 2KB [16][64] block per step.
#define S3_T 65536

typedef short short8 __attribute__((ext_vector_type(8)));   // 8 x bf16 (4 VGPRs)
typedef float f32x4 __attribute__((ext_vector_type(4)));    // MFMA accumulator
typedef unsigned int uint2v __attribute__((ext_vector_type(2)));
typedef unsigned int uint4v __attribute__((ext_vector_type(4)));

__device__ inline float bf2f(unsigned short u) {
    union { unsigned int i; float f; } v; v.i = ((unsigned int)u) << 16; return v.f;
}
__device__ inline unsigned short f2bf(float f) {
    union { float f; unsigned int i; } v; v.f = f;
    unsigned int i = v.i;
    unsigned int r = (i + 0x7fffu + ((i >> 16) & 1u)) >> 16;  // RNE
    return (unsigned short)r;
}

// ---------------------------------------------------------------------------
// Generic fp32 (K x N) -> bf16 (N x K) tile transpose.  src[k][n] -> dst[n][k]
// ---------------------------------------------------------------------------
__global__ void wt_transpose(const float* __restrict__ src,
                             unsigned short* __restrict__ dst, int K, int N) {
    __shared__ float tile[32][33];
    int n0 = blockIdx.x * 32, k0 = blockIdx.y * 32;
    int tx = threadIdx.x, ty = threadIdx.y;
    for (int i = ty; i < 32; i += 8)
        tile[i][tx] = src[(size_t)(k0 + i) * N + n0 + tx];
    __syncthreads();
    for (int i = ty; i < 32; i += 8)
        dst[(size_t)(n0 + i) * K + k0 + tx] = f2bf(tile[tx][i]);
}

// ---------------------------------------------------------------------------
// x (B,F,T) fp32 -> xT (T,B,F) bf16.  grid: 4096 blocks, 256 thr
// ---------------------------------------------------------------------------
__global__ void xpose_x(const float* __restrict__ x, unsigned short* __restrict__ xT) {
    __shared__ float tile[64][65];
    int id = blockIdx.x;
    int b = id >> 6;            // 0..63
    int ft = (id >> 4) & 3;     // 0..3   (F/64)
    int tt = id & 15;           // 0..15  (T/64)
    int f0 = ft * 64, t0 = tt * 64;
    for (int i = threadIdx.x; i < 64 * 64; i += 256) {
        int fl = i >> 6, tl = i & 63;
        tile[fl][tl] = x[((size_t)(b * F_ + f0 + fl)) * T_ + t0 + tl];
    }
    __syncthreads();
    for (int i = threadIdx.x; i < 64 * 64; i += 256) {
        int tl = i >> 6, fl = i & 63;
        xT[((size_t)(t0 + tl) * B_ + b) * F_ + f0 + fl] = f2bf(tile[fl][tl]);
    }
}

// ---------------------------------------------------------------------------
// Input projection into S3 layout:
//   S3(t, b, h) = bf16( xT[t*64+b][:] @ Wx[:,h] + bias[h] )
// grid: (16, 1024); block 256 (4 waves). MFMA 16x16x32 layouts (HW-verified):
//   A frag: m = lane&15, k = (lane>>4)*8 + j
//   B frag: n = lane&15, k = (lane>>4)*8 + j
//   C/D   : col = lane&15, row = (lane>>4)*4 + r
// ---------------------------------------------------------------------------
__global__ __launch_bounds__(256) void proj_kernel(
    const unsigned short* __restrict__ xT, const unsigned short* __restrict__ WxT,
    const float* __restrict__ bias, unsigned short* __restrict__ S) {
    int nb = blockIdx.x;   // 0..15
    int mb = blockIdx.y;   // 0..1023 (= t)
    int wave = threadIdx.x >> 6, lane = threadIdx.x & 63;
    int col16 = lane & 15, quad = lane >> 4;
    int m0 = mb * 64 + wave * 16;
    int n0 = nb * 64;

    f32x4 acc[4];
    for (int s = 0; s < 4; ++s)
        for (int r = 0; r < 4; ++r) acc[s][r] = 0.0f;

    #pragma unroll
    for (int kc = 0; kc < F_ / 32; ++kc) {
        int k0 = kc * 32 + quad * 8;
        short8 a = *reinterpret_cast<const short8*>(xT + (size_t)(m0 + col16) * F_ + k0);
        #pragma unroll
        for (int s = 0; s < 4; ++s) {
            short8 bfr = *reinterpret_cast<const short8*>(
                WxT + (size_t)(n0 + s * 16 + col16) * F_ + k0);
            acc[s] = __builtin_amdgcn_mfma_f32_16x16x32_bf16(a, bfr, acc[s], 0, 0, 0);
        }
    }
    #pragma unroll
    for (int s = 0; s < 4; ++s) {
        int col = n0 + s * 16 + col16;
        float bb = bias[col];
        #pragma unroll
        for (int r = 0; r < 4; ++r) {
            int brow = wave * 16 + quad * 4 + r;   // batch row 0..63
            size_t off = (size_t)mb * S3_T + (size_t)(brow >> 4) * 16384 +
                         (size_t)(col >> 6) * 1024 + (brow & 15) * 64 + (col & 63);
            S[off] = f2bf(acc[s][r] + bb);
        }
    }
}

// ---------------------------------------------------------------------------
// Zero the barrier flags. Runs each launch (re-poison safe).
// ---------------------------------------------------------------------------
__global__ void init_flags(unsigned int* flags) {
    if (threadIdx.x < NWG) flags[threadIdx.x * 16] = 0;
}

// ---------------------------------------------------------------------------
// Persistent recurrence, zero cache-maintenance design:
//   h stores   : sc0 sc1 (write-through to LLC = agent coherence point)
//   h loads (A): sc0 sc1 (read LLC directly; bypass possibly-stale L1/L2)
//   Wh loads   : normal (read-only, L2 stays HOT all 1024 steps - no inv!)
//   flags      : relaxed agent atomics (proven visible, round 4); release =
//                per-wave vmcnt(0) + __syncthreads + one flag store. No wbL2.
// Partition: WG (rg,cg) owns rows rg*16..+16, cols cg*64..+64. A-tile (16 rows
// x 1024 k = 32KB) staged in LDS once per step, shared by 4 waves (16 cols ea).
// Barrier groups = 16 WGs (one rg) -> independent progress per row-group.
// ---------------------------------------------------------------------------
__global__ __launch_bounds__(256, 1) void rnn_persistent(
    unsigned short* __restrict__ S, const unsigned short* __restrict__ WhT,
    unsigned int* flags) {
    const int bid = blockIdx.x;
    const int rg = bid >> 4;                   // 0..3
    const int cg = bid & 15;                   // 0..15
    const int tid = threadIdx.x;
    const int wave = tid >> 6, lane = tid & 63;
    const int col16 = lane & 15, quad = lane >> 4;

    // LDS A-tile, layout [kc 32][quad 4][m 16][8 elems] (ushorts) = 32KB.
    // ds_write: per-wave contiguous 1KB. ds_read (MFMA frag): per-quad-group
    // contiguous 256B. Both conflict-free.
    __shared__ unsigned short Atile[16 * 1024];

    unsigned int* myflag = &flags[(rg * 16 + cg) * 16];

    // ---- t = 0: h0 = tanh(xp0), sc1 write-through so step-1 readers see it ----
    {
        unsigned short* St0 = S + (size_t)rg * 16384 + (size_t)cg * 1024;
        const unsigned short* sp = St0 + tid * 4;
        unsigned short h0 = f2bf(tanhf(bf2f(sp[0])));
        unsigned short h1 = f2bf(tanhf(bf2f(sp[1])));
        unsigned short h2 = f2bf(tanhf(bf2f(sp[2])));
        unsigned short h3 = f2bf(tanhf(bf2f(sp[3])));
        uint2v pk;
        pk[0] = (unsigned int)h0 | ((unsigned int)h1 << 16);
        pk[1] = (unsigned int)h2 | ((unsigned int)h3 << 16);
        asm volatile("global_store_dwordx2 %0, %1, off sc0 sc1"
                     :: "v"((unsigned long long)(uintptr_t)(St0 + tid * 4)), "v"(pk)
                     : "memory");
    }
    asm volatile("s_waitcnt vmcnt(0)" ::: "memory");
    __syncthreads();
    if (tid == 0)
        __hip_atomic_store(myflag, 1u, __ATOMIC_RELAXED, __HIP_MEMORY_SCOPE_AGENT);

    int dead = 0;

    for (int t = 1; t < T_; ++t) {
        unsigned short* Stb = S + (size_t)t * S3_T + (size_t)rg * 16384 + (size_t)cg * 1024;
        const unsigned short* Ablk = S + (size_t)(t - 1) * S3_T + (size_t)rg * 16384;

        // xp prefetch (own block; only proj wrote it; normal cached load OK)
        float xp[4];
        #pragma unroll
        for (int r = 0; r < 4; ++r)
            xp[r] = bf2f(Stb[(quad * 4 + r) * 64 + wave * 16 + col16]);

        // ---- group barrier: wait for my row-group's 16 WGs at step t-1 ----
        if (wave == 0 && !dead) {
            const unsigned tgt = (unsigned)t;
            int guard = 0;
            while (true) {
                unsigned v = __hip_atomic_load(&flags[(rg * 16 + (lane & 15)) * 16],
                                               __ATOMIC_RELAXED, __HIP_MEMORY_SCOPE_AGENT);
                if (__ballot(v >= tgt) == ~0ull) break;
                __builtin_amdgcn_s_sleep(1);
                if (++guard > (1 << 16)) { dead = 1; break; }  // fast fail, never hang
            }
        }
        asm volatile("" ::: "memory");
        __syncthreads();

        // ---- stage A (16 rows x 1024 k, 32KB) to LDS via sc1 LLC reads ----
        // thread chunk i: m = tid&15, kblk = i*16 + (tid>>4)  (kblk = k/8)
        uint4v av[8];
        #pragma unroll
        for (int i = 0; i < 8; ++i) {
            int kblk = i * 16 + (tid >> 4);
            int m = tid & 15;
            const unsigned short* gp = Ablk + ((kblk >> 3) * 1024 + m * 64 + (kblk & 7) * 8);
            asm volatile("global_load_dwordx4 %0, %1, off sc0 sc1"
                         : "=v"(av[i])
                         : "v"((unsigned long long)(uintptr_t)gp));
        }
        asm volatile("s_waitcnt vmcnt(0)" ::: "memory");
        __builtin_amdgcn_sched_barrier(0);
        #pragma unroll
        for (int i = 0; i < 8; ++i) {
            int kblk = i * 16 + (tid >> 4);
            int m = tid & 15;
            int l16 = (kblk >> 2) * 64 + (kblk & 3) * 16 + m;   // 16B-chunk index
            *reinterpret_cast<uint4v*>(&Atile[l16 * 8]) = av[i];
        }
        __syncthreads();

        // ---- wave computes 16 rows x 16 cols, K=1024 (2 indep MFMA chains) ----
        f32x4 acc0 = {0.f, 0.f, 0.f, 0.f};
        f32x4 acc1 = {0.f, 0.f, 0.f, 0.f};
        const int nglob = cg * 64 + wave * 16 + col16;
        const unsigned short* Brow = WhT + (size_t)nglob * 1024 + quad * 8;
        const unsigned short* Abase = Atile + quad * 128 + col16 * 8;
        #pragma unroll
        for (int kc = 0; kc < 32; kc += 2) {
            short8 a0 = *reinterpret_cast<const short8*>(Abase + kc * 512);
            short8 a1 = *reinterpret_cast<const short8*>(Abase + (kc + 1) * 512);
            short8 b0 = *reinterpret_cast<const short8*>(Brow + kc * 32);
            short8 b1 = *reinterpret_cast<const short8*>(Brow + (kc + 1) * 32);
            acc0 = __builtin_amdgcn_mfma_f32_16x16x32_bf16(a0, b0, acc0, 0, 0, 0);
            acc1 = __builtin_amdgcn_mfma_f32_16x16x32_bf16(a1, b1, acc1, 0, 0, 0);
        }

        // ---- tanh + sc1 write-through h stores ----
        #pragma unroll
        for (int r = 0; r < 4; ++r) {
            float h = tanhf(xp[r] + acc0[r] + acc1[r]);
            unsigned int hv = (unsigned int)f2bf(h);
            unsigned short* dp = Stb + (quad * 4 + r) * 64 + wave * 16 + col16;
            asm volatile("global_store_short %0, %1, off sc0 sc1"
                         :: "v"((unsigned long long)(uintptr_t)dp), "v"(hv)
                         : "memory");
        }
        asm volatile("s_waitcnt vmcnt(0)" ::: "memory");
        __syncthreads();
        if (tid == 0)
            __hip_atomic_store(myflag, (unsigned)(t + 1), __ATOMIC_RELAXED,
                               __HIP_MEMORY_SCOPE_AGENT);
    }
}

// ---------------------------------------------------------------------------
// Output projection: out[b][t][o] = S3row(t,b,:) @ Wout[:,o] + bout[o]
// grid: (8, 1024); block 256 (4 waves).
// ---------------------------------------------------------------------------
__global__ __launch_bounds__(256) void out_kernel(
    const unsigned short* __restrict__ S, const unsigned short* __restrict__ WoutT,
    const float* __restrict__ bout, float* __restrict__ out) {
    int nb = blockIdx.x;   // 0..7
    int tt = blockIdx.y;   // 0..1023 (= t)
    int wave = threadIdx.x >> 6, lane = threadIdx.x & 63;
    int col16 = lane & 15, quad = lane >> 4;
    int n0 = nb * 64;

    f32x4 acc[4];
    for (int s = 0; s < 4; ++s)
        for (int r = 0; r < 4; ++r) acc[s][r] = 0.0f;

    // A row b = wave*16 + col16: base into S3[t][b>>4][...][b&15][...]
    const unsigned short* arow =
        S + (size_t)tt * S3_T + (size_t)wave * 16384 + (size_t)col16 * 64 + quad * 8;

    #pragma unroll 4
    for (int kc = 0; kc < H_ / 32; ++kc) {
        int k0 = kc * 32 + quad * 8;
        short8 a = *reinterpret_cast<const short8*>(arow + (kc >> 1) * 1024 + (kc & 1) * 32);
        #pragma unroll
        for (int s = 0; s < 4; ++s) {
            short8 bfr = *reinterpret_cast<const short8*>(
                WoutT + (size_t)(n0 + s * 16 + col16) * H_ + k0);
            acc[s] = __builtin_amdgcn_mfma_f32_16x16x32_bf16(a, bfr, acc[s], 0, 0, 0);
        }
    }
    #pragma unroll
    for (int s = 0; s < 4; ++s) {
        int col = n0 + s * 16 + col16;
        float bo = bout[col];
        #pragma unroll
        for (int r = 0; r < 4; ++r) {
            int bidx = wave * 16 + quad * 4 + r;   // batch index within this t
            out[((size_t)bidx * T_ + tt) * O_ + col] = acc[s][r] + bo;
        }
    }
}

// ---------------------------------------------------------------------------
extern "C" void kernel_launch(void* const* d_in, const int* in_sizes, int n_in,
                              void* d_out, int out_size, void* d_ws, size_t ws_size,
                              hipStream_t stream) {
    const float* x    = (const float*)d_in[0];   // (B,F,T)
    const float* Wx   = (const float*)d_in[1];   // (F,H)
    const float* Wh   = (const float*)d_in[2];   // (H,H)
    const float* bias = (const float*)d_in[3];   // (H)
    const float* Wout = (const float*)d_in[4];   // (H,O)
    const float* bout = (const float*)d_in[5];   // (O)
    float* out = (float*)d_out;

    // workspace layout (bf16 = ushort), total ~131.5 MB
    unsigned short* WhT   = (unsigned short*)d_ws;             // H x H   [n][k]
    unsigned short* WxT   = WhT + (size_t)H_ * H_;             // H x F   [n][k]
    unsigned short* WoutT = WxT + (size_t)H_ * F_;             // O x H   [n][k]
    unsigned short* S     = WoutT + (size_t)O_ * H_;           // S3: T x 4 x 16 x 16 x 64
    unsigned short* xT    = (unsigned short*)d_out;            // T x B x F scratch (32MB, consumed by proj)
    // barrier flags: in d_out past xT scratch (out_kernel overwrites later — safe)
    unsigned int* flags   = (unsigned int*)((char*)d_out + (32u << 20));

    wt_transpose<<<dim3(H_ / 32, H_ / 32), dim3(32, 8), 0, stream>>>(Wh, WhT, H_, H_);
    wt_transpose<<<dim3(H_ / 32, F_ / 32), dim3(32, 8), 0, stream>>>(Wx, WxT, F_, H_);
    wt_transpose<<<dim3(O_ / 32, H_ / 32), dim3(32, 8), 0, stream>>>(Wout, WoutT, H_, O_);
    xpose_x<<<dim3(4096), dim3(256), 0, stream>>>(x, xT);
    init_flags<<<1, 64, 0, stream>>>(flags);

    proj_kernel<<<dim3(16, 1024), dim3(256), 0, stream>>>(xT, WxT, bias, S);

    // all T recurrence steps in one persistent-grid dispatch
    rnn_persistent<<<dim3(NWG), dim3(256), 0, stream>>>(S, WhT, flags);

    out_kernel<<<dim3(8, 1024), dim3(256), 0, stream>>>(S, WoutT, bout, out);
}

// Round 6
// 6625.569 us; speedup vs baseline: 1.4329x; 1.1354x over previous
//
#include <hip/hip_runtime.h>
#include <math.h>

// Problem dims (fixed)
#define B_ 64
#define F_ 256
#define T_ 1024
#define H_ 1024
#define O_ 512

// RNN decomposition: 4 independent chains (16 batch rows each) x 16 WGs
// (64 cols each).  Chain c = bids {c, c+8, ..., c+120} of a 128-block launch
// -> co-XCD under round-robin dispatch (verified at runtime, never assumed).
#define NCHAIN 4
#define NMEM   16

// Blocked state layout S3[t][rg][cg][mr=16][c=64] (elems):
//   elem(t,b,n) = t*65536 + (b>>4)*16384 + (n>>6)*1024 + (b&15)*64 + (n&63)
#define S3_T 65536

typedef short short8 __attribute__((ext_vector_type(8)));   // 8 x bf16 (4 VGPRs)
typedef float f32x4 __attribute__((ext_vector_type(4)));    // MFMA accumulator
typedef unsigned int uint4v __attribute__((ext_vector_type(4)));
typedef unsigned long long ull;

__device__ inline float bf2f(unsigned short u) {
    union { unsigned int i; float f; } v; v.i = ((unsigned int)u) << 16; return v.f;
}
__device__ inline unsigned short f2bf(float f) {
    union { float f; unsigned int i; } v; v.f = f;
    unsigned int i = v.i;
    unsigned int r = (i + 0x7fffu + ((i >> 16) & 1u)) >> 16;  // RNE
    return (unsigned short)r;
}

// ---------------------------------------------------------------------------
// fp32 (K x N) -> bf16 (N x K) transpose.  grid: (N/32, K/32), block: (32,8)
// ---------------------------------------------------------------------------
__global__ void wt_transpose(const float* __restrict__ src,
                             unsigned short* __restrict__ dst, int K, int N) {
    __shared__ float tile[32][33];
    int n0 = blockIdx.x * 32, k0 = blockIdx.y * 32;
    int tx = threadIdx.x, ty = threadIdx.y;
    for (int i = ty; i < 32; i += 8)
        tile[i][tx] = src[(size_t)(k0 + i) * N + n0 + tx];
    __syncthreads();
    for (int i = ty; i < 32; i += 8)
        dst[(size_t)(n0 + i) * K + k0 + tx] = f2bf(tile[tx][i]);
}

// ---------------------------------------------------------------------------
// x (B,F,T) fp32 -> xT (T,B,F) bf16.  grid: 4096 blocks, 256 thr
// ---------------------------------------------------------------------------
__global__ void xpose_x(const float* __restrict__ x, unsigned short* __restrict__ xT) {
    __shared__ float tile[64][65];
    int id = blockIdx.x;
    int b = id >> 6;
    int ft = (id >> 4) & 3;
    int tt = id & 15;
    int f0 = ft * 64, t0 = tt * 64;
    for (int i = threadIdx.x; i < 64 * 64; i += 256) {
        int fl = i >> 6, tl = i & 63;
        tile[fl][tl] = x[((size_t)(b * F_ + f0 + fl)) * T_ + t0 + tl];
    }
    __syncthreads();
    for (int i = threadIdx.x; i < 64 * 64; i += 256) {
        int tl = i >> 6, fl = i & 63;
        xT[((size_t)(t0 + tl) * B_ + b) * F_ + f0 + fl] = f2bf(tile[fl][tl]);
    }
}

// ---------------------------------------------------------------------------
// Input projection into S3: S3(t,b,h) = bf16( xT[t*64+b][:] @ Wx[:,h] + bias )
// grid: (16, 1024); block 256 (4 waves). MFMA 16x16x32 layouts (HW-verified).
// ---------------------------------------------------------------------------
__global__ __launch_bounds__(256) void proj_kernel(
    const unsigned short* __restrict__ xT, const unsigned short* __restrict__ WxT,
    const float* __restrict__ bias, unsigned short* __restrict__ S) {
    int nb = blockIdx.x;
    int mb = blockIdx.y;   // = t
    int wave = threadIdx.x >> 6, lane = threadIdx.x & 63;
    int col16 = lane & 15, quad = lane >> 4;
    int m0 = mb * 64 + wave * 16;
    int n0 = nb * 64;

    f32x4 acc[4];
    for (int s = 0; s < 4; ++s)
        for (int r = 0; r < 4; ++r) acc[s][r] = 0.0f;

    #pragma unroll
    for (int kc = 0; kc < F_ / 32; ++kc) {
        int k0 = kc * 32 + quad * 8;
        short8 a = *reinterpret_cast<const short8*>(xT + (size_t)(m0 + col16) * F_ + k0);
        #pragma unroll
        for (int s = 0; s < 4; ++s) {
            short8 bfr = *reinterpret_cast<const short8*>(
                WxT + (size_t)(n0 + s * 16 + col16) * F_ + k0);
            acc[s] = __builtin_amdgcn_mfma_f32_16x16x32_bf16(a, bfr, acc[s], 0, 0, 0);
        }
    }
    #pragma unroll
    for (int s = 0; s < 4; ++s) {
        int col = n0 + s * 16 + col16;
        float bb = bias[col];
        #pragma unroll
        for (int r = 0; r < 4; ++r) {
            int brow = wave * 16 + quad * 4 + r;
            size_t off = (size_t)mb * S3_T + (size_t)(brow >> 4) * 16384 +
                         (size_t)(col >> 6) * 1024 + (brow & 15) * 64 + (col & 63);
            S[off] = f2bf(acc[s][r] + bb);
        }
    }
}

// ---------------------------------------------------------------------------
// Zero the control block (flags + setup + tokens). Re-poison safe.
// ---------------------------------------------------------------------------
__global__ void init_ctrl(unsigned int* ctrl) {
    for (int i = threadIdx.x; i < 8192; i += 256) ctrl[i] = 0u;
}

// ---------------------------------------------------------------------------
// Protocol helpers.
// LOCAL  = all 16 members of the chain verified on ONE XCD: plain writeback
//          stores/loads (step-unique addresses -> always cache-fresh) + L2-point
//          atomics for flags (global_atomic without sc1 executes at the XCD L2
//          and architecturally bypasses L1).
// GLOBAL = round-5 agent/LLC protocol (write-through sc0 sc1 data, agent-scope
//          relaxed atomic flags). Proven correct on HW.
// ---------------------------------------------------------------------------
template<bool LOCAL>
__device__ __forceinline__ void st_h(unsigned short* p, unsigned short v) {
    if (LOCAL) {
        *p = v;
    } else {
        asm volatile("global_store_short %0, %1, off sc0 sc1"
                     :: "v"((ull)(uintptr_t)p), "v"((unsigned int)v) : "memory");
    }
}

template<bool LOCAL>
__device__ __forceinline__ void flag_store(unsigned int* p, unsigned int v) {
    if (LOCAL) {
        asm volatile("global_atomic_swap %0, %1, off"
                     :: "v"((ull)(uintptr_t)p), "v"(v) : "memory");
    } else {
        __hip_atomic_store(p, v, __ATOMIC_RELAXED, __HIP_MEMORY_SCOPE_AGENT);
    }
}

template<bool LOCAL>
__device__ __forceinline__ unsigned int flag_load(unsigned int* p) {
    unsigned int old;
    if (LOCAL) {
        asm volatile("global_atomic_add %0, %1, %2, off sc0\n\t"
                     "s_waitcnt vmcnt(0)"
                     : "=v"(old) : "v"((ull)(uintptr_t)p), "v"(0u) : "memory");
    } else {
        old = __hip_atomic_load(p, __ATOMIC_RELAXED, __HIP_MEMORY_SCOPE_AGENT);
    }
    return old;
}

// ---------------------------------------------------------------------------
// Main recurrence loop (templated on protocol).
// WG = (chain, m): rows chain*16..+16, cols m*64..+64.  B (Wh slice) in LDS.
// Per step: poll 16 member flags -> read A (16 x 1024 h of prev step) straight
// from cache -> 32+32 MFMAs (2 chains) -> tanh -> store own 2KB block -> flag.
// ---------------------------------------------------------------------------
template<bool LOCAL>
__device__ void rnn_loop(unsigned short* S, const unsigned short* Bs,
                         unsigned int* ctrl, int chain, int m, int tid) {
    const int wave = tid >> 6, lane = tid & 63;
    const int col16 = lane & 15, quad = lane >> 4;
    unsigned int* myflag = &ctrl[(chain * 16 + m) * 32];

    // ---- t = 0: h0 = tanh(xp0) ----
    {
        unsigned short* St0 = S + (size_t)chain * 16384 + (size_t)m * 1024;
        #pragma unroll
        for (int i = 0; i < 4; ++i) {
            int e = tid * 4 + i;
            st_h<LOCAL>(&St0[e], f2bf(tanhf(bf2f(St0[e]))));
        }
    }
    asm volatile("s_waitcnt vmcnt(0)" ::: "memory");
    __syncthreads();
    if (tid == 0) flag_store<LOCAL>(myflag, 1u);

    int dead = 0;

    for (int t = 1; t < T_; ++t) {
        unsigned short* Stb = S + (size_t)t * S3_T + (size_t)chain * 16384 + (size_t)m * 1024;
        const unsigned short* Ab = S + (size_t)(t - 1) * S3_T + (size_t)chain * 16384;

        // xp prefetch (own block, written only by proj / this WG — race-free)
        float xp[4];
        #pragma unroll
        for (int r = 0; r < 4; ++r)
            xp[r] = bf2f(Stb[(quad * 4 + r) * 64 + wave * 16 + col16]);
        asm volatile("s_waitcnt vmcnt(0)" ::: "memory");  // drain before poll/K-loop

        // ---- chain barrier: all 16 members finished step t-1 ----
        if (wave == 0 && !dead) {
            const unsigned int tgt = (unsigned int)t;
            int g = 0;
            while (true) {
                unsigned int v = flag_load<LOCAL>(&ctrl[(chain * 16 + (lane & 15)) * 32]);
                if (__ballot(v >= tgt) == ~0ull) break;
                if (!LOCAL) __builtin_amdgcn_s_sleep(1);
                if (++g > (1 << 17)) { dead = 1; break; }  // fast fail, never hang
            }
        }
        __syncthreads();

        // ---- K loop: A direct from cache, B from LDS ----
        f32x4 acc0 = {0.f, 0.f, 0.f, 0.f};
        f32x4 acc1 = {0.f, 0.f, 0.f, 0.f};
        const unsigned short* Arow  = Ab + col16 * 64 + quad * 8;
        const unsigned short* Bslab = Bs + wave * 16384 + quad * 128 + col16 * 8;
        if (LOCAL) {
            #pragma unroll
            for (int kc2 = 0; kc2 < 16; ++kc2) {
                short8 a0 = *reinterpret_cast<const short8*>(Arow + kc2 * 1024);
                short8 a1 = *reinterpret_cast<const short8*>(Arow + kc2 * 1024 + 32);
                short8 b0 = *reinterpret_cast<const short8*>(Bslab + (2 * kc2) * 512);
                short8 b1 = *reinterpret_cast<const short8*>(Bslab + (2 * kc2 + 1) * 512);
                acc0 = __builtin_amdgcn_mfma_f32_16x16x32_bf16(a0, b0, acc0, 0, 0, 0);
                acc1 = __builtin_amdgcn_mfma_f32_16x16x32_bf16(a1, b1, acc1, 0, 0, 0);
            }
        } else {
            for (int kc2 = 0; kc2 < 16; ++kc2) {
                short8 a0, a1;
                ull p0 = (ull)(uintptr_t)(Arow + kc2 * 1024);
                ull p1 = p0 + 64;
                asm volatile("global_load_dwordx4 %0, %2, off sc0 sc1\n\t"
                             "global_load_dwordx4 %1, %3, off sc0 sc1\n\t"
                             "s_waitcnt vmcnt(0)"
                             : "=v"(a0), "=v"(a1) : "v"(p0), "v"(p1) : "memory");
                __builtin_amdgcn_sched_barrier(0);
                short8 b0 = *reinterpret_cast<const short8*>(Bslab + (2 * kc2) * 512);
                short8 b1 = *reinterpret_cast<const short8*>(Bslab + (2 * kc2 + 1) * 512);
                acc0 = __builtin_amdgcn_mfma_f32_16x16x32_bf16(a0, b0, acc0, 0, 0, 0);
                acc1 = __builtin_amdgcn_mfma_f32_16x16x32_bf16(a1, b1, acc1, 0, 0, 0);
            }
        }

        // ---- tanh + store own 2KB block ----
        #pragma unroll
        for (int r = 0; r < 4; ++r) {
            float h = tanhf(xp[r] + acc0[r] + acc1[r]);
            st_h<LOCAL>(Stb + (quad * 4 + r) * 64 + wave * 16 + col16, f2bf(h));
        }
        asm volatile("s_waitcnt vmcnt(0)" ::: "memory");
        __syncthreads();
        if (tid == 0) flag_store<LOCAL>(myflag, (unsigned int)(t + 1));
    }
}

// ---------------------------------------------------------------------------
// Persistent recurrence kernel.  128 blocks launched; bid%8>=4 exit (surplus
// to spread workers across XCDs); workers: chain = bid&7, member m = bid>>3.
// Startup: fill B in LDS; publish XCC_ID (agent) + coherence token (normal
// store); one agent-scope ready barrier; each chain decides LOCAL vs GLOBAL
// from (a) XCC_ID uniformity AND (b) functional token visibility. Decision is
// deterministic and identical across members. Placement never assumed.
// ---------------------------------------------------------------------------
__global__ __launch_bounds__(256, 1) void rnn_persistent(
    unsigned short* __restrict__ S, const unsigned short* __restrict__ WhT,
    unsigned int* ctrl) {
    const int bid = blockIdx.x;
    if ((bid & 7) >= NCHAIN) return;           // surplus block
    const int chain = bid & 7;                 // 0..3
    const int m = bid >> 3;                    // 0..15
    const int tid = threadIdx.x;
    const int wave = tid >> 6, lane = tid & 63;
    const int w = chain * 16 + m;              // worker index 0..63

    __shared__ unsigned short Bs[64 * 1024];   // Wh slice [cols 64][K 1024], swizzled
    __shared__ int s_proto;

    // ---- fill B slab (one-time): swizzled [wave'][kc][quad][col16][8e] ----
    {
        const int n0 = m * 64;
        for (int i = tid; i < 8192; i += 256) {
            int c = i >> 7, j = i & 127;
            int kc = j >> 2, q = j & 3;
            int dst = (c >> 4) * 16384 + kc * 512 + q * 128 + (c & 15) * 8;
            *reinterpret_cast<uint4v*>(&Bs[dst]) =
                *reinterpret_cast<const uint4v*>(WhT + (size_t)(n0 + c) * 1024 + j * 8);
        }
    }

    unsigned int* flags = ctrl;                 // [w*32]
    unsigned int* ready = &ctrl[2048];
    unsigned int* xcds  = &ctrl[2560];          // [w*32]
    unsigned int* toks  = &ctrl[5120];          // [w*32]

    // ---- publish: token (normal store) + xcd (agent) + ready inc ----
    unsigned int xcd = 0;
    asm volatile("s_getreg_b32 %0, hwreg(HW_REG_XCC_ID)" : "=s"(xcd));
    if (tid == 0) {
        toks[w * 32] = (unsigned int)(w + 1);   // normal writeback store
        asm volatile("s_waitcnt vmcnt(0)" ::: "memory");
        __hip_atomic_store(&xcds[w * 32], xcd + 1u, __ATOMIC_RELAXED,
                           __HIP_MEMORY_SCOPE_AGENT);
        __hip_atomic_fetch_add(ready, 1u, __ATOMIC_RELEASE, __HIP_MEMORY_SCOPE_AGENT);
    }
    __syncthreads();

    // ---- wait for all 64 workers (agent scope, bounded) ----
    if (tid == 0) {
        int g = 0, got = 0;
        while (true) {
            unsigned int v = __hip_atomic_load(ready, __ATOMIC_RELAXED,
                                               __HIP_MEMORY_SCOPE_AGENT);
            if (v >= 64u) { got = 1; break; }
            __builtin_amdgcn_s_sleep(2);
            if (++g > (1 << 20)) break;
        }
        s_proto = got ? -1 : 0;                 // 0 = forced GLOBAL
    }
    __syncthreads();

    // ---- decide protocol (wave 0; all members read identical data) ----
    if (wave == 0) {
        int mm = lane & 15;
        unsigned int xv = __hip_atomic_load(&xcds[(chain * 16 + mm) * 32],
                                            __ATOMIC_RELAXED, __HIP_MEMORY_SCOPE_AGENT);
        unsigned int tv = toks[(chain * 16 + mm) * 32];   // normal load (cold line)
        unsigned int x0 = __shfl(xv, 0);
        bool uni = (__ballot(xv == x0) == ~0ull) && (x0 != 0u);
        bool tok = (__ballot(tv == (unsigned int)(chain * 16 + mm + 1)) == ~0ull);
        if (lane == 0) s_proto = (s_proto != 0 && uni && tok) ? 1 : 0;
    }
    __syncthreads();
    const int local_ok = s_proto;

    if (local_ok) rnn_loop<true>(S, Bs, ctrl, chain, m, tid);
    else          rnn_loop<false>(S, Bs, ctrl, chain, m, tid);
}

// ---------------------------------------------------------------------------
// Output projection: out[b][t][o] = S3row(t,b,:) @ Wout[:,o] + bout[o]
// grid: (8, 1024); block 256 (4 waves).
// ---------------------------------------------------------------------------
__global__ __launch_bounds__(256) void out_kernel(
    const unsigned short* __restrict__ S, const unsigned short* __restrict__ WoutT,
    const float* __restrict__ bout, float* __restrict__ out) {
    int nb = blockIdx.x;
    int tt = blockIdx.y;   // = t
    int wave = threadIdx.x >> 6, lane = threadIdx.x & 63;
    int col16 = lane & 15, quad = lane >> 4;
    int n0 = nb * 64;

    f32x4 acc[4];
    for (int s = 0; s < 4; ++s)
        for (int r = 0; r < 4; ++r) acc[s][r] = 0.0f;

    const unsigned short* arow =
        S + (size_t)tt * S3_T + (size_t)wave * 16384 + (size_t)col16 * 64 + quad * 8;

    #pragma unroll 4
    for (int kc = 0; kc < H_ / 32; ++kc) {
        int k0 = kc * 32 + quad * 8;
        short8 a = *reinterpret_cast<const short8*>(arow + (kc >> 1) * 1024 + (kc & 1) * 32);
        #pragma unroll
        for (int s = 0; s < 4; ++s) {
            short8 bfr = *reinterpret_cast<const short8*>(
                WoutT + (size_t)(n0 + s * 16 + col16) * H_ + k0);
            acc[s] = __builtin_amdgcn_mfma_f32_16x16x32_bf16(a, bfr, acc[s], 0, 0, 0);
        }
    }
    #pragma unroll
    for (int s = 0; s < 4; ++s) {
        int col = n0 + s * 16 + col16;
        float bo = bout[col];
        #pragma unroll
        for (int r = 0; r < 4; ++r) {
            int bidx = wave * 16 + quad * 4 + r;
            out[((size_t)bidx * T_ + tt) * O_ + col] = acc[s][r] + bo;
        }
    }
}

// ---------------------------------------------------------------------------
extern "C" void kernel_launch(void* const* d_in, const int* in_sizes, int n_in,
                              void* d_out, int out_size, void* d_ws, size_t ws_size,
                              hipStream_t stream) {
    const float* x    = (const float*)d_in[0];   // (B,F,T)
    const float* Wx   = (const float*)d_in[1];   // (F,H)
    const float* Wh   = (const float*)d_in[2];   // (H,H)
    const float* bias = (const float*)d_in[3];   // (H)
    const float* Wout = (const float*)d_in[4];   // (H,O)
    const float* bout = (const float*)d_in[5];   // (O)
    float* out = (float*)d_out;

    // workspace layout (bf16 = ushort), total ~131.5 MB
    unsigned short* WhT   = (unsigned short*)d_ws;             // H x H   [n][k]
    unsigned short* WxT   = WhT + (size_t)H_ * H_;             // H x F   [n][k]
    unsigned short* WoutT = WxT + (size_t)H_ * F_;             // O x H   [n][k]
    unsigned short* S     = WoutT + (size_t)O_ * H_;           // S3: T x 4 x 16 x 16 x 64
    unsigned short* xT    = (unsigned short*)d_out;            // T x B x F scratch (32MB)
    // control block (flags/setup/tokens): in d_out past xT scratch
    unsigned int* ctrl    = (unsigned int*)((char*)d_out + (32u << 20));

    wt_transpose<<<dim3(H_ / 32, H_ / 32), dim3(32, 8), 0, stream>>>(Wh, WhT, H_, H_);
    wt_transpose<<<dim3(H_ / 32, F_ / 32), dim3(32, 8), 0, stream>>>(Wx, WxT, F_, H_);
    wt_transpose<<<dim3(O_ / 32, H_ / 32), dim3(32, 8), 0, stream>>>(Wout, WoutT, H_, O_);
    xpose_x<<<dim3(4096), dim3(256), 0, stream>>>(x, xT);
    init_ctrl<<<1, 256, 0, stream>>>(ctrl);

    proj_kernel<<<dim3(16, 1024), dim3(256), 0, stream>>>(xT, WxT, bias, S);

    // all T recurrence steps in one persistent-grid dispatch (128 blocks:
    // 64 workers spread across XCDs + 64 surplus that exit immediately)
    rnn_persistent<<<dim3(128), dim3(256), 0, stream>>>(S, WhT, ctrl);

    out_kernel<<<dim3(8, 1024), dim3(256), 0, stream>>>(S, WoutT, bout, out);
}

// Round 10
// 6025.505 us; speedup vs baseline: 1.5756x; 1.0996x over previous
//
#include <hip/hip_runtime.h>
#include <math.h>

// Problem dims (fixed)
#define B_ 64
#define F_ 256
#define T_ 1024
#define H_ 1024
#define O_ 512

// RNN decomposition: 4 independent chains (16 batch rows each) x 16 WGs
// (64 cols each), 256-thread (4-wave) WGs.  Chain c = bids === c (mod 8) of a
// 128-block launch -> co-XCD under round-robin dispatch (verified at runtime).
#define NCHAIN 4
#define NMEM   16

// Blocked state layout S3[t][rg][cg][mr=16][c=64] (elems):
//   elem(t,b,n) = t*65536 + (b>>4)*16384 + (n>>6)*1024 + (b&15)*64 + (n&63)
#define S3_T 65536

typedef short short8 __attribute__((ext_vector_type(8)));   // 8 x bf16 (4 VGPRs)
typedef float f32x4 __attribute__((ext_vector_type(4)));    // MFMA accumulator
typedef unsigned int uint4v __attribute__((ext_vector_type(4)));
typedef unsigned long long ull;

__device__ inline float bf2f(unsigned short u) {
    union { unsigned int i; float f; } v; v.i = ((unsigned int)u) << 16; return v.f;
}
__device__ inline unsigned short f2bf(float f) {
    union { float f; unsigned int i; } v; v.f = f;
    unsigned int i = v.i;
    unsigned int r = (i + 0x7fffu + ((i >> 16) & 1u)) >> 16;  // RNE
    return (unsigned short)r;
}

// ---------------------------------------------------------------------------
// fp32 (K x N) -> bf16 (N x K) transpose.  grid: (N/32, K/32), block: (32,8)
// ---------------------------------------------------------------------------
__global__ void wt_transpose(const float* __restrict__ src,
                             unsigned short* __restrict__ dst, int K, int N) {
    __shared__ float tile[32][33];
    int n0 = blockIdx.x * 32, k0 = blockIdx.y * 32;
    int tx = threadIdx.x, ty = threadIdx.y;
    for (int i = ty; i < 32; i += 8)
        tile[i][tx] = src[(size_t)(k0 + i) * N + n0 + tx];
    __syncthreads();
    for (int i = ty; i < 32; i += 8)
        dst[(size_t)(n0 + i) * K + k0 + tx] = f2bf(tile[tx][i]);
}

// ---------------------------------------------------------------------------
// x (B,F,T) fp32 -> xT (T,B,F) bf16.  grid: 4096 blocks, 256 thr
// ---------------------------------------------------------------------------
__global__ void xpose_x(const float* __restrict__ x, unsigned short* __restrict__ xT) {
    __shared__ float tile[64][65];
    int id = blockIdx.x;
    int b = id >> 6;
    int ft = (id >> 4) & 3;
    int tt = id & 15;
    int f0 = ft * 64, t0 = tt * 64;
    for (int i = threadIdx.x; i < 64 * 64; i += 256) {
        int fl = i >> 6, tl = i & 63;
        tile[fl][tl] = x[((size_t)(b * F_ + f0 + fl)) * T_ + t0 + tl];
    }
    __syncthreads();
    for (int i = threadIdx.x; i < 64 * 64; i += 256) {
        int tl = i >> 6, fl = i & 63;
        xT[((size_t)(t0 + tl) * B_ + b) * F_ + f0 + fl] = f2bf(tile[fl][tl]);
    }
}

// ---------------------------------------------------------------------------
// Input projection into S3: S3(t,b,h) = bf16( xT[t*64+b][:] @ Wx[:,h] + bias )
// grid: (16, 1024); block 256 (4 waves). MFMA 16x16x32 layouts (HW-verified).
// ---------------------------------------------------------------------------
__global__ __launch_bounds__(256) void proj_kernel(
    const unsigned short* __restrict__ xT, const unsigned short* __restrict__ WxT,
    const float* __restrict__ bias, unsigned short* __restrict__ S) {
    int nb = blockIdx.x;
    int mb = blockIdx.y;   // = t
    int wave = threadIdx.x >> 6, lane = threadIdx.x & 63;
    int col16 = lane & 15, quad = lane >> 4;
    int m0 = mb * 64 + wave * 16;
    int n0 = nb * 64;

    f32x4 acc[4];
    for (int s = 0; s < 4; ++s)
        for (int r = 0; r < 4; ++r) acc[s][r] = 0.0f;

    #pragma unroll
    for (int kc = 0; kc < F_ / 32; ++kc) {
        int k0 = kc * 32 + quad * 8;
        short8 a = *reinterpret_cast<const short8*>(xT + (size_t)(m0 + col16) * F_ + k0);
        #pragma unroll
        for (int s = 0; s < 4; ++s) {
            short8 bfr = *reinterpret_cast<const short8*>(
                WxT + (size_t)(n0 + s * 16 + col16) * F_ + k0);
            acc[s] = __builtin_amdgcn_mfma_f32_16x16x32_bf16(a, bfr, acc[s], 0, 0, 0);
        }
    }
    #pragma unroll
    for (int s = 0; s < 4; ++s) {
        int col = n0 + s * 16 + col16;
        float bb = bias[col];
        #pragma unroll
        for (int r = 0; r < 4; ++r) {
            int brow = wave * 16 + quad * 4 + r;
            size_t off = (size_t)mb * S3_T + (size_t)(brow >> 4) * 16384 +
                         (size_t)(col >> 6) * 1024 + (brow & 15) * 64 + (col & 63);
            S[off] = f2bf(acc[s][r] + bb);
        }
    }
}

// ---------------------------------------------------------------------------
// Zero the control block (fan-out flags + setup + tokens). Re-poison safe.
// ---------------------------------------------------------------------------
__global__ void init_ctrl(unsigned int* ctrl) {
    for (int i = threadIdx.x; i < 24576; i += 256) ctrl[i] = 0u;
}

// ---------------------------------------------------------------------------
// Protocol helpers.  Round-8 lesson: on gfx950, plain AND bare-sc0 loads may
// hit stale L1 lines (sc0 = workgroup scope, L1 hits allowed) — a spinning
// poll NEVER sees the update and the guard trips.  Cross-WG visibility is
// only proven via (a) atomic RMW (executes at L2, r6-proven) or (b) sc0 sc1
// system-scope ops (LLC, r4/r5-proven).  LOCAL uses (a); GLOBAL uses (b).
// ---------------------------------------------------------------------------
template<bool LOCAL>
__device__ __forceinline__ void st_h(unsigned short* p, unsigned short v) {
    if (LOCAL) {
        *p = v;   // write-through to XCD L2 (r6-proven)
    } else {
        asm volatile("global_store_short %0, %1, off sc0 sc1"
                     :: "v"((ull)(uintptr_t)p), "v"((unsigned int)v) : "memory");
    }
}

template<bool LOCAL>
__device__ __forceinline__ void flag_store(unsigned int* p, unsigned int v) {
    if (LOCAL) {
        asm volatile("global_atomic_swap %0, %1, off"
                     :: "v"((ull)(uintptr_t)p), "v"(v) : "memory");
    } else {
        __hip_atomic_store(p, v, __ATOMIC_RELAXED, __HIP_MEMORY_SCOPE_AGENT);
    }
}

template<bool LOCAL>
__device__ __forceinline__ unsigned int flag_load(unsigned int* p) {
    unsigned int old;
    if (LOCAL) {
        // atomic RMW: architecturally executes at L2 — never L1-cached (r6-proven)
        asm volatile("global_atomic_add %0, %1, %2, off sc0\n\t"
                     "s_waitcnt vmcnt(0)"
                     : "=v"(old) : "v"((ull)(uintptr_t)p), "v"(0u) : "memory");
    } else {
        old = __hip_atomic_load(p, __ATOMIC_RELAXED, __HIP_MEMORY_SCOPE_AGENT);
    }
    return old;
}

// ---------------------------------------------------------------------------
// Main recurrence loop (r6 structure).  WG = (chain, m): rows chain*16..+16,
// cols m*64..+64 (FULL 128B-line ownership — no partner half-lines).  B (Wh
// 64-col slice) in 128KB LDS.  Per wave: 16 cols, K=1024, 32 MFMAs; A-loads
// hoisted (all 32 in flight, one exposed latency).
// Barrier: FAN-OUT flag matrix fan[consumer][producer] (64B stride) — each
// producer swaps 16 private copies; each consumer RMW-polls only its own row
// (uncontended; lanes<16 only).  Guard -> fast wrong-answer, never hang.
// ---------------------------------------------------------------------------
template<bool LOCAL>
__device__ void rnn_loop(unsigned short* S, const unsigned short* Bs,
                         unsigned int* ctrl, int chain, int m, int tid) {
    const int wave = tid >> 6, lane = tid & 63;
    const int col16 = lane & 15, quad = lane >> 4;
    unsigned int* fan = ctrl;   // word idx ((chain*16+cons)*16 + prod)*16

    // ---- t = 0: h0 = tanh(xp0) ----
    {
        unsigned short* St0 = S + (size_t)chain * 16384 + (size_t)m * 1024;
        #pragma unroll
        for (int i = 0; i < 4; ++i) {
            int e = tid * 4 + i;
            st_h<LOCAL>(&St0[e], f2bf(tanhf(bf2f(St0[e]))));
        }
    }
    asm volatile("s_waitcnt vmcnt(0)" ::: "memory");
    __syncthreads();
    if (wave == 0 && lane < 16)
        flag_store<LOCAL>(&fan[(((unsigned)chain * 16 + lane) * 16 + m) * 16], 1u);

    int dead = 0;

    for (int t = 1; t < T_; ++t) {
        unsigned short* Stb = S + (size_t)t * S3_T + (size_t)chain * 16384 + (size_t)m * 1024;
        const unsigned short* Ab = S + (size_t)(t - 1) * S3_T + (size_t)chain * 16384;

        // xp prefetch (own block, full own lines; race-free) — overlaps poll
        float xp[4];
        #pragma unroll
        for (int r = 0; r < 4; ++r)
            xp[r] = bf2f(Stb[(quad * 4 + r) * 64 + wave * 16 + col16]);
        asm volatile("s_waitcnt vmcnt(0)" ::: "memory");

        // ---- chain barrier: poll OWN row of the fan matrix (uncontended) ----
        if (wave == 0 && !dead) {
            const unsigned tgt = (unsigned)t;
            unsigned int* myrow = &fan[(((unsigned)chain * 16 + m) * 16) * 16];
            int g = 0;
            while (true) {
                unsigned v = 0xffffffffu;
                if (lane < 16) v = flag_load<LOCAL>(myrow + lane * 16);
                if (__ballot(v >= tgt) == ~0ull) break;
                if (!LOCAL) __builtin_amdgcn_s_sleep(1);
                if (++g > (1 << 17)) { dead = 1; break; }  // fast fail, never hang
            }
        }
        __syncthreads();

        // ---- hoisted A loads: 32 x 16B per wave, single exposed latency ----
        const unsigned short* Arow = Ab + col16 * 64 + quad * 8;
        short8 a[32];
        if (LOCAL) {
            #pragma unroll
            for (int kc2 = 0; kc2 < 16; ++kc2) {
                a[2 * kc2]     = *reinterpret_cast<const short8*>(Arow + kc2 * 1024);
                a[2 * kc2 + 1] = *reinterpret_cast<const short8*>(Arow + kc2 * 1024 + 32);
            }
        } else {
            #pragma unroll
            for (int kc2 = 0; kc2 < 16; ++kc2) {
                ull p0 = (ull)(uintptr_t)(Arow + kc2 * 1024);
                asm volatile("global_load_dwordx4 %0, %2, off sc0 sc1\n\t"
                             "global_load_dwordx4 %1, %3, off sc0 sc1"
                             : "=v"(a[2 * kc2]), "=v"(a[2 * kc2 + 1])
                             : "v"(p0), "v"(p0 + 64));
            }
            asm volatile("s_waitcnt vmcnt(0)" ::: "memory");
            __builtin_amdgcn_sched_barrier(0);
        }

        // ---- K loop: 32 MFMAs from registers, B from LDS ----
        f32x4 acc0 = {0.f, 0.f, 0.f, 0.f};
        f32x4 acc1 = {0.f, 0.f, 0.f, 0.f};
        const unsigned short* Bslab = Bs + wave * 16384 + quad * 128 + col16 * 8;
        #pragma unroll
        for (int kc2 = 0; kc2 < 16; ++kc2) {
            short8 b0 = *reinterpret_cast<const short8*>(Bslab + (2 * kc2) * 512);
            short8 b1 = *reinterpret_cast<const short8*>(Bslab + (2 * kc2 + 1) * 512);
            acc0 = __builtin_amdgcn_mfma_f32_16x16x32_bf16(a[2 * kc2], b0, acc0, 0, 0, 0);
            acc1 = __builtin_amdgcn_mfma_f32_16x16x32_bf16(a[2 * kc2 + 1], b1, acc1, 0, 0, 0);
        }

        // ---- tanh + store own 16-col slice ----
        #pragma unroll
        for (int r = 0; r < 4; ++r) {
            float h = tanhf(xp[r] + acc0[r] + acc1[r]);
            st_h<LOCAL>(Stb + (quad * 4 + r) * 64 + wave * 16 + col16, f2bf(h));
        }
        asm volatile("s_waitcnt vmcnt(0)" ::: "memory");
        __syncthreads();
        if (wave == 0 && lane < 16)
            flag_store<LOCAL>(&fan[(((unsigned)chain * 16 + lane) * 16 + m) * 16],
                              (unsigned)(t + 1));
    }
}

// ---------------------------------------------------------------------------
// Persistent recurrence kernel (r6 structure).  128 blocks; (bid&7)>=4 exit;
// workers: chain = bid&7, member m = bid>>3 (0..15).  Startup: fill B LDS
// slab, publish XCC_ID (agent) + coherence token (normal store), agent ready
// barrier, then each chain picks LOCAL vs GLOBAL from (a) XCC uniformity AND
// (b) functional plain-store visibility.  Placement never assumed.
// ---------------------------------------------------------------------------
__global__ __launch_bounds__(256, 1) void rnn_persistent(
    unsigned short* __restrict__ S, const unsigned short* __restrict__ WhT,
    unsigned int* ctrl) {
    const int bid = blockIdx.x;
    if ((bid & 7) >= NCHAIN) return;           // surplus block
    const int chain = bid & 7;                 // 0..3
    const int m = bid >> 3;                    // 0..15
    const int tid = threadIdx.x;
    const int wave = tid >> 6, lane = tid & 63;
    const int w = chain * 16 + m;              // worker index 0..63

    __shared__ unsigned short Bs[64 * 1024];   // Wh slice [wave][kc][q8][col16][8]
    __shared__ int s_proto;

    // ---- fill B slab (one-time) ----
    {
        const int n0g = m * 64;
        for (int i = tid; i < 8192; i += 256) {
            int c = i >> 7, j = i & 127;
            int dst = (c >> 4) * 16384 + (j >> 2) * 512 + (j & 3) * 128 + (c & 15) * 8;
            *reinterpret_cast<uint4v*>(&Bs[dst]) =
                *reinterpret_cast<const uint4v*>(WhT + (size_t)(n0g + c) * 1024 + j * 8);
        }
    }

    // ctrl layout: fan [0,16384) ; ready 16384 ; xcds 16448+w*32 ; toks 18496+w*32
    unsigned int* ready = &ctrl[16384];
    unsigned int* xcds  = &ctrl[16448];
    unsigned int* toks  = &ctrl[18496];

    // ---- publish: token (normal store) + xcd (agent) + ready inc ----
    unsigned int xcd = 0;
    asm volatile("s_getreg_b32 %0, hwreg(HW_REG_XCC_ID)" : "=s"(xcd));
    if (tid == 0) {
        toks[w * 32] = (unsigned int)(w + 1);   // normal writeback store
        asm volatile("s_waitcnt vmcnt(0)" ::: "memory");
        __hip_atomic_store(&xcds[w * 32], xcd + 1u, __ATOMIC_RELAXED,
                           __HIP_MEMORY_SCOPE_AGENT);
        __hip_atomic_fetch_add(ready, 1u, __ATOMIC_RELEASE, __HIP_MEMORY_SCOPE_AGENT);
    }
    __syncthreads();

    // ---- wait for all 64 workers (agent scope, bounded) ----
    if (tid == 0) {
        int g = 0, got = 0;
        while (true) {
            unsigned int v = __hip_atomic_load(ready, __ATOMIC_RELAXED,
                                               __HIP_MEMORY_SCOPE_AGENT);
            if (v >= 64u) { got = 1; break; }
            __builtin_amdgcn_s_sleep(2);
            if (++g > (1 << 20)) break;
        }
        s_proto = got ? -1 : 0;                 // 0 = forced GLOBAL
    }
    __syncthreads();

    // ---- decide protocol (wave 0; all members read identical data) ----
    if (wave == 0) {
        int mm = lane & 15;
        unsigned int xv = __hip_atomic_load(&xcds[(chain * 16 + mm) * 32],
                                            __ATOMIC_RELAXED, __HIP_MEMORY_SCOPE_AGENT);
        unsigned int tv = toks[(chain * 16 + mm) * 32];   // normal load (cold line)
        unsigned int x0 = __shfl(xv, 0);
        bool uni = (__ballot(xv == x0) == ~0ull) && (x0 != 0u);
        bool tok = (__ballot(tv == (unsigned int)(chain * 16 + mm + 1)) == ~0ull);
        if (lane == 0) s_proto = (s_proto != 0 && uni && tok) ? 1 : 0;
    }
    __syncthreads();
    const int local_ok = s_proto;

    if (local_ok) rnn_loop<true>(S, Bs, ctrl, chain, m, tid);
    else          rnn_loop<false>(S, Bs, ctrl, chain, m, tid);
}

// ---------------------------------------------------------------------------
// Output projection: out[b][t][o] = S3row(t,b,:) @ Wout[:,o] + bout[o]
// grid: (8, 1024); block 256 (4 waves).
// ---------------------------------------------------------------------------
__global__ __launch_bounds__(256) void out_kernel(
    const unsigned short* __restrict__ S, const unsigned short* __restrict__ WoutT,
    const float* __restrict__ bout, float* __restrict__ out) {
    int nb = blockIdx.x;
    int tt = blockIdx.y;   // = t
    int wave = threadIdx.x >> 6, lane = threadIdx.x & 63;
    int col16 = lane & 15, quad = lane >> 4;
    int n0 = nb * 64;

    f32x4 acc[4];
    for (int s = 0; s < 4; ++s)
        for (int r = 0; r < 4; ++r) acc[s][r] = 0.0f;

    const unsigned short* arow =
        S + (size_t)tt * S3_T + (size_t)wave * 16384 + (size_t)col16 * 64 + quad * 8;

    #pragma unroll 4
    for (int kc = 0; kc < H_ / 32; ++kc) {
        int k0 = kc * 32 + quad * 8;
        short8 a = *reinterpret_cast<const short8*>(arow + (kc >> 1) * 1024 + (kc & 1) * 32);
        #pragma unroll
        for (int s = 0; s < 4; ++s) {
            short8 bfr = *reinterpret_cast<const short8*>(
                WoutT + (size_t)(n0 + s * 16 + col16) * H_ + k0);
            acc[s] = __builtin_amdgcn_mfma_f32_16x16x32_bf16(a, bfr, acc[s], 0, 0, 0);
        }
    }
    #pragma unroll
    for (int s = 0; s < 4; ++s) {
        int col = n0 + s * 16 + col16;
        float bo = bout[col];
        #pragma unroll
        for (int r = 0; r < 4; ++r) {
            int bidx = wave * 16 + quad * 4 + r;
            out[((size_t)bidx * T_ + tt) * O_ + col] = acc[s][r] + bo;
        }
    }
}

// ---------------------------------------------------------------------------
extern "C" void kernel_launch(void* const* d_in, const int* in_sizes, int n_in,
                              void* d_out, int out_size, void* d_ws, size_t ws_size,
                              hipStream_t stream) {
    const float* x    = (const float*)d_in[0];   // (B,F,T)
    const float* Wx   = (const float*)d_in[1];   // (F,H)
    const float* Wh   = (const float*)d_in[2];   // (H,H)
    const float* bias = (const float*)d_in[3];   // (H)
    const float* Wout = (const float*)d_in[4];   // (H,O)
    const float* bout = (const float*)d_in[5];   // (O)
    float* out = (float*)d_out;

    // workspace layout (bf16 = ushort), total ~131.5 MB
    unsigned short* WhT   = (unsigned short*)d_ws;             // H x H   [n][k]
    unsigned short* WxT   = WhT + (size_t)H_ * H_;             // H x F   [n][k]
    unsigned short* WoutT = WxT + (size_t)H_ * F_;             // O x H   [n][k]
    unsigned short* S     = WoutT + (size_t)O_ * H_;           // S3: T x 4 x 16 x 16 x 64
    unsigned short* xT    = (unsigned short*)d_out;            // T x B x F scratch (32MB)
    // control block (fan flags/setup/tokens): in d_out past xT scratch
    unsigned int* ctrl    = (unsigned int*)((char*)d_out + (32u << 20));

    wt_transpose<<<dim3(H_ / 32, H_ / 32), dim3(32, 8), 0, stream>>>(Wh, WhT, H_, H_);
    wt_transpose<<<dim3(H_ / 32, F_ / 32), dim3(32, 8), 0, stream>>>(Wx, WxT, F_, H_);
    wt_transpose<<<dim3(O_ / 32, H_ / 32), dim3(32, 8), 0, stream>>>(Wout, WoutT, H_, O_);
    xpose_x<<<dim3(4096), dim3(256), 0, stream>>>(x, xT);
    init_ctrl<<<1, 256, 0, stream>>>(ctrl);

    proj_kernel<<<dim3(16, 1024), dim3(256), 0, stream>>>(xT, WxT, bias, S);

    // all T recurrence steps in one persistent-grid dispatch (128 blocks:
    // 64 workers + 64 surplus that exit immediately)
    rnn_persistent<<<dim3(128), dim3(256), 0, stream>>>(S, WhT, ctrl);

    out_kernel<<<dim3(8, 1024), dim3(256), 0, stream>>>(S, WoutT, bout, out);
}